// Round 7
// baseline (666.881 us; speedup 1.0000x reference)
//
#include <hip/hip_runtime.h>

typedef __bf16 bf16;
typedef __bf16 bf16x4 __attribute__((ext_vector_type(4)));
typedef __bf16 bf16x8 __attribute__((ext_vector_type(8)));
typedef float f32x4 __attribute__((ext_vector_type(4)));

#define S 2048
#define DM 2048
#define HD 128
#define H 16
#define NQKV 3072
#define NEWTON_ITERS 12

__device__ __forceinline__ void gl2lds16(const void* g, void* l) {
    __builtin_amdgcn_global_load_lds(
        (const __attribute__((address_space(1))) void*)g,
        (__attribute__((address_space(3))) void*)l, 16, 0, 0);
}

__device__ __forceinline__ void nt_store4(f32x4 v, float* p) {
    __builtin_nontemporal_store(v, (f32x4*)p);
}

// ---------------- fused fp32 -> bf16 convert for all 5 inputs (float4 granules) ----------------
__global__ void cvt_all(const float* __restrict__ hid, const float* __restrict__ wq,
                        const float* __restrict__ wk, const float* __restrict__ wv,
                        const float* __restrict__ wo, bf16* __restrict__ bh,
                        bf16* __restrict__ bqkv, bf16* __restrict__ bwo) {
    int i = blockIdx.x * blockDim.x + threadIdx.x;
    const float* src;
    bf16* dst;
    int off;
    if (i < 1048576) { src = hid; dst = bh; off = i; }
    else if (i < 2097152) { src = wq; dst = bqkv; off = i - 1048576; }
    else if (i < 2359296) { src = wk; dst = bqkv + 2048 * 2048; off = i - 2097152; }
    else if (i < 2621440) { src = wv; dst = bqkv + 2048 * 2048 + 512 * 2048; off = i - 2359296; }
    else { src = wo; dst = bwo; off = i - 2621440; }
    float4 f = ((const float4*)src)[off];
    bf16x4 o;
    o[0] = (bf16)f.x; o[1] = (bf16)f.y; o[2] = (bf16)f.z; o[3] = (bf16)f.w;
    ((bf16x4*)dst)[off] = o;
}

// ---------------- 128x128-tile GEMM: C[m][n] = sum_k A[m][k]*B[n][k] ----------------
__global__ __launch_bounds__(256) void gemm128_bt(const bf16* __restrict__ A,
                                                  const bf16* __restrict__ B,
                                                  float* __restrict__ C, int Ndim, int K) {
    __shared__ bf16 As[128 * 32];
    __shared__ bf16 Bs[128 * 32];
    int m0 = blockIdx.x * 128, n0 = blockIdx.y * 128;
    int t = threadIdx.x;
    int l = t & 63, w = t >> 6;
    int lane16 = l & 15, quad = l >> 4;

    int c0 = (w * 2) * 64 + l;
    int c1 = c0 + 64;
    const bf16* Abase = A + (size_t)m0 * K;
    const bf16* Bbase = B + (size_t)n0 * K;

    int wm = (w & 1) * 64, wn = (w >> 1) * 64;
    f32x4 acc[4][4];
#pragma unroll
    for (int i = 0; i < 4; i++)
#pragma unroll
        for (int j = 0; j < 4; j++) acc[i][j] = (f32x4){0.f, 0.f, 0.f, 0.f};

    for (int k0 = 0; k0 < K; k0 += 32) {
        gl2lds16(Abase + (size_t)(c0 >> 2) * K + k0 + (c0 & 3) * 8, &As[(w * 2) * 512]);
        gl2lds16(Abase + (size_t)(c1 >> 2) * K + k0 + (c1 & 3) * 8, &As[(w * 2 + 1) * 512]);
        gl2lds16(Bbase + (size_t)(c0 >> 2) * K + k0 + (c0 & 3) * 8, &Bs[(w * 2) * 512]);
        gl2lds16(Bbase + (size_t)(c1 >> 2) * K + k0 + (c1 & 3) * 8, &Bs[(w * 2 + 1) * 512]);
        __syncthreads();
        bf16x8 af[4], bfr[4];
#pragma unroll
        for (int i = 0; i < 4; i++)
            af[i] = *(const bf16x8*)&As[(wm + i * 16 + lane16) * 32 + quad * 8];
#pragma unroll
        for (int j = 0; j < 4; j++)
            bfr[j] = *(const bf16x8*)&Bs[(wn + j * 16 + lane16) * 32 + quad * 8];
#pragma unroll
        for (int i = 0; i < 4; i++)
#pragma unroll
            for (int j = 0; j < 4; j++)
                acc[i][j] = __builtin_amdgcn_mfma_f32_16x16x32_bf16(af[i], bfr[j], acc[i][j], 0, 0, 0);
        __syncthreads();
    }
#pragma unroll
    for (int i = 0; i < 4; i++)
#pragma unroll
        for (int j = 0; j < 4; j++) {
            float* cp = C + (size_t)(m0 + wm + i * 16 + quad * 4) * Ndim + n0 + wn + j * 16 + lane16;
#pragma unroll
            for (int r = 0; r < 4; r++) cp[(size_t)r * Ndim] = acc[i][j][r];
        }
}

// ---------------- RoPE for q/k (cols 0..2559), coalesced in col ----------------
__global__ void rope_qk(const float* __restrict__ qkv, const float* __restrict__ cosb,
                        const float* __restrict__ sinb, bf16* __restrict__ qs,
                        bf16* __restrict__ kb) {
    int col = blockIdx.x * 256 + threadIdx.x;  // 0..2559
    int s = blockIdx.y;
    const float* row = qkv + (size_t)s * NQKV;
    float v = row[col];
    if (col < DM) {
        int h = col >> 7, d = col & 127;
        float c = cosb[s * HD + d], sn = sinb[s * HD + d];
        float other = row[(h << 7) + ((d < 64) ? (d + 64) : (d - 64))];
        float rot = (d < 64) ? -other : other;
        float o = v * c + rot * sn;
        qs[((size_t)h * S + s) * HD + d] = (bf16)(o * 0.04419417382415922f);  // HD^-0.5 * (alpha-1)
    } else {
        int c2 = col - DM;
        int kv = c2 >> 7, d = c2 & 127;
        float c = cosb[s * HD + d], sn = sinb[s * HD + d];
        float other = row[DM + (kv << 7) + ((d < 64) ? (d + 64) : (d - 64))];
        float rot = (d < 64) ? -other : other;
        float o = v * c + rot * sn;
        kb[((size_t)kv * S + s) * HD + d] = (bf16)o;
    }
}

// ---------------- V transpose via LDS tile: qkv[s][2560+y] -> vT[y][s] bf16 ----------------
__global__ __launch_bounds__(256) void vtrans(const float* __restrict__ qkv, bf16* __restrict__ vT) {
    __shared__ bf16 tile[64][66];
    int s0 = blockIdx.x * 64, y0 = blockIdx.y * 64;
    int t = threadIdx.x;
    int ty = t & 63, tr = t >> 6;
#pragma unroll
    for (int i = 0; i < 16; i++) {
        int s = tr + i * 4;
        float v = qkv[(size_t)(s0 + s) * NQKV + 2560 + y0 + ty];  // coalesced read
        tile[s][ty] = (bf16)v;
    }
    __syncthreads();
#pragma unroll
    for (int i = 0; i < 16; i++) {
        int y = tr + i * 4;
        vT[(size_t)(y0 + y) * S + s0 + ty] = tile[ty][y];  // coalesced write
    }
}

// ------- fused: scores (MFMA) + causal mask + entmax Newton + P.V (MFMA) + attn write -------
// Ping-pong LDS buffer -> ONE barrier per segment in Phase A and C (was two).
// Newton (monotone from below on convex f) replaces bisection: 12 iters, never overshoots.
// attn global stores issued after the last barrier, nontemporal.
template <int SEGS>
__device__ __forceinline__ void attn_body(const bf16* __restrict__ qs, const bf16* __restrict__ kb,
                                          const bf16* __restrict__ vT, float* __restrict__ attn,
                                          bf16* __restrict__ o, int r0, int h,
                                          float (&buf)[2][16][532]) {
    constexpr int NREG = SEGS * 8;
    int jlen = r0 + 16;
    int l = threadIdx.x & 63;
    int w = threadIdx.x >> 6;
    int lane16 = l & 15, quad = l >> 4;

    const bf16* qrow = qs + ((size_t)h * S + (r0 + lane16)) * HD + quad * 8;
    bf16x8 afrag[4];
#pragma unroll
    for (int kc = 0; kc < 4; kc++) afrag[kc] = *(const bf16x8*)(qrow + kc * 32);

    const bf16* kbase = kb + (size_t)(h >> 2) * S * HD;
    const bf16* vbase = vT + (size_t)(h >> 2) * HD * S;
    float xr[NREG];

    // ---- Phase A: scores into registers; ping-pong buffer, 1 barrier/segment ----
#pragma unroll
    for (int sgi = 0; sgi < SEGS; sgi++) {
        int j0 = sgi * 512;
        float (*sb)[532] = buf[sgi & 1];
#pragma unroll
        for (int tt = 0; tt < 2; tt++) {
            int t = w + tt * 16;
            int jt = j0 + t * 16;
            if (jt < jlen) {
                f32x4 acc = {0.f, 0.f, 0.f, 0.f};
                const bf16* kp = kbase + (size_t)(jt + lane16) * HD + quad * 8;
#pragma unroll
                for (int kc = 0; kc < 4; kc++) {
                    bf16x8 b = *(const bf16x8*)(kp + kc * 32);
                    acc = __builtin_amdgcn_mfma_f32_16x16x32_bf16(afrag[kc], b, acc, 0, 0, 0);
                }
                if (jt + 15 > r0) {  // diagonal tile: apply causal mask
                    int jj = jt + lane16;
#pragma unroll
                    for (int r = 0; r < 4; r++) {
                        int rowi = quad * 4 + r;
                        float v = acc[r];
                        if (jj > r0 + rowi) v = -1e30f;
                        sb[rowi][t * 16 + lane16] = v;
                    }
                } else {
#pragma unroll
                    for (int r = 0; r < 4; r++) sb[quad * 4 + r][t * 16 + lane16] = acc[r];
                }
            }
        }
        __syncthreads();
        if (sgi == SEGS - 1) {  // diagonal segment: mask out-of-range pulls
#pragma unroll
            for (int part = 0; part < 2; part++) {
                float4 f = *(const float4*)&sb[w][part * 256 + l * 4];
                int jb = j0 + part * 256 + l * 4;
                xr[sgi * 8 + part * 4 + 0] = (jb + 0 < jlen) ? f.x : -1e30f;
                xr[sgi * 8 + part * 4 + 1] = (jb + 1 < jlen) ? f.y : -1e30f;
                xr[sgi * 8 + part * 4 + 2] = (jb + 2 < jlen) ? f.z : -1e30f;
                xr[sgi * 8 + part * 4 + 3] = (jb + 3 < jlen) ? f.w : -1e30f;
            }
        } else {
#pragma unroll
            for (int part = 0; part < 2; part++) {
                float4 f = *(const float4*)&sb[w][part * 256 + l * 4];
                xr[sgi * 8 + part * 4 + 0] = f.x;
                xr[sgi * 8 + part * 4 + 1] = f.y;
                xr[sgi * 8 + part * 4 + 2] = f.z;
                xr[sgi * 8 + part * 4 + 3] = f.w;
            }
        }
        // no trailing barrier: next segment writes the other buffer
    }

    // ---- Phase B: entmax-1.5 tau via safeguarded Newton (wave w owns row r0+w) ----
    float m = -1e30f;
#pragma unroll
    for (int c = 0; c < NREG; c++) m = fmaxf(m, xr[c]);
#pragma unroll
    for (int off = 1; off < 64; off <<= 1) m = fmaxf(m, __shfl_xor(m, off));

    float tau = m - 1.0f;  // f(tau) >= 1 here; Newton from below never overshoots (f convex)
#pragma unroll 1
    for (int it = 0; it < NEWTON_ITERS; it++) {
        float f0 = 0.f, f1 = 0.f, f2 = 0.f, f3 = 0.f;
        float g0 = 0.f, g1 = 0.f, g2 = 0.f, g3 = 0.f;
#pragma unroll
        for (int c = 0; c < NREG; c += 4) {
            float t0 = fmaxf(xr[c + 0] - tau, 0.f); f0 = fmaf(t0, t0, f0); g0 += t0;
            float t1 = fmaxf(xr[c + 1] - tau, 0.f); f1 = fmaf(t1, t1, f1); g1 += t1;
            float t2 = fmaxf(xr[c + 2] - tau, 0.f); f2 = fmaf(t2, t2, f2); g2 += t2;
            float t3 = fmaxf(xr[c + 3] - tau, 0.f); f3 = fmaf(t3, t3, f3); g3 += t3;
        }
        float f = (f0 + f1) + (f2 + f3);
        float g = (g0 + g1) + (g2 + g3);
#pragma unroll
        for (int off = 1; off < 64; off <<= 1) {
            f += __shfl_xor(f, off);
            g += __shfl_xor(g, off);
        }
        tau += (f - 1.0f) / (2.0f * g + 1e-20f);
    }

    float s0 = 0.f, s1 = 0.f, s2 = 0.f, s3 = 0.f;
#pragma unroll
    for (int c = 0; c < NREG; c += 4) {
        float t0 = fmaxf(xr[c + 0] - tau, 0.f); s0 = fmaf(t0, t0, s0);
        float t1 = fmaxf(xr[c + 1] - tau, 0.f); s1 = fmaf(t1, t1, s1);
        float t2 = fmaxf(xr[c + 2] - tau, 0.f); s2 = fmaf(t2, t2, s2);
        float t3 = fmaxf(xr[c + 3] - tau, 0.f); s3 = fmaf(t3, t3, s3);
    }
    float ssum = (s0 + s1) + (s2 + s3);
#pragma unroll
    for (int off = 1; off < 64; off <<= 1) ssum += __shfl_xor(ssum, off);
    float inv = 1.0f / ssum;

    // ---- Phase C: P -> LDS bf16 (ping-pong), P.V MFMA; 1 barrier/segment ----
    int jt_o = (w & 7) * 16;
    int kh = (w >> 3) * 256;
    f32x4 acc_o = {0.f, 0.f, 0.f, 0.f};

    __syncthreads();  // cover A-pulls / C-writes hazard on buffer 0
#pragma unroll
    for (int sgi = 0; sgi < SEGS; sgi++) {
        int j0 = sgi * 512;
        bf16 (*pbf)[552] = (bf16(*)[552])(&buf[sgi & 1][0][0]);
#pragma unroll
        for (int part = 0; part < 2; part++) {
            float t0 = fmaxf(xr[sgi * 8 + part * 4 + 0] - tau, 0.f);
            float t1 = fmaxf(xr[sgi * 8 + part * 4 + 1] - tau, 0.f);
            float t2 = fmaxf(xr[sgi * 8 + part * 4 + 2] - tau, 0.f);
            float t3 = fmaxf(xr[sgi * 8 + part * 4 + 3] - tau, 0.f);
            bf16x4 pbv;
            pbv[0] = (bf16)(t0 * t0 * inv); pbv[1] = (bf16)(t1 * t1 * inv);
            pbv[2] = (bf16)(t2 * t2 * inv); pbv[3] = (bf16)(t3 * t3 * inv);
            *(bf16x4*)&pbf[w][part * 256 + l * 4] = pbv;
        }
        __syncthreads();
#pragma unroll
        for (int ks = 0; ks < 8; ks++) {
            int kk = kh + ks * 32;
            bf16x8 a = *(const bf16x8*)&pbf[lane16][kk + quad * 8];
            bf16x8 b = *(const bf16x8*)(vbase + (size_t)(jt_o + lane16) * S + j0 + kk + quad * 8);
            acc_o = __builtin_amdgcn_mfma_f32_16x16x32_bf16(a, b, acc_o, 0, 0, 0);
        }
        // no trailing barrier: next segment writes the other buffer
    }

    // ---- Phase D: combine K-halves, write O ----
    __syncthreads();
    if (w >= 8) {
#pragma unroll
        for (int r = 0; r < 4; r++) buf[0][w - 8][l * 4 + r] = acc_o[r];
    }
    __syncthreads();
    if (w < 8) {
        bf16* op = o + (size_t)(r0 + quad * 4) * DM + h * HD + jt_o + lane16;
#pragma unroll
        for (int r = 0; r < 4; r++) {
            float v = acc_o[r] + buf[0][w][l * 4 + r];
            op[(size_t)r * DM] = (bf16)v;
        }
    }

    // ---- Phase E: attn global write (nontemporal, after the last barrier) ----
    float* arow = attn + ((size_t)h * S + (r0 + w)) * S;
#pragma unroll
    for (int sgi = 0; sgi < SEGS; sgi++) {
        int j0 = sgi * 512;
#pragma unroll
        for (int part = 0; part < 2; part++) {
            float t0 = fmaxf(xr[sgi * 8 + part * 4 + 0] - tau, 0.f);
            float t1 = fmaxf(xr[sgi * 8 + part * 4 + 1] - tau, 0.f);
            float t2 = fmaxf(xr[sgi * 8 + part * 4 + 2] - tau, 0.f);
            float t3 = fmaxf(xr[sgi * 8 + part * 4 + 3] - tau, 0.f);
            f32x4 pv;
            pv[0] = t0 * t0 * inv; pv[1] = t1 * t1 * inv;
            pv[2] = t2 * t2 * inv; pv[3] = t3 * t3 * inv;
            nt_store4(pv, &arow[j0 + part * 256 + l * 4]);
        }
    }
    f32x4 z4 = {0.f, 0.f, 0.f, 0.f};
    for (int j = SEGS * 512 + l * 4; j < S; j += 256) nt_store4(z4, &arow[j]);
}

__global__ __launch_bounds__(1024) void attn_av_all(const bf16* __restrict__ qs,
                                                    const bf16* __restrict__ kb,
                                                    const bf16* __restrict__ vT,
                                                    float* __restrict__ attn,
                                                    bf16* __restrict__ o) {
    __shared__ float buf[2][16][532];  // 68 KB: score ping-pong; P-buffer + O-combine alias into it
    int qb = 127 - blockIdx.x;  // heavy blocks dispatched first
    int h = blockIdx.y;
    int r0 = qb * 16;
    int nseg = (qb >> 5) + 1;
    switch (nseg) {
        case 1: attn_body<1>(qs, kb, vT, attn, o, r0, h, buf); break;
        case 2: attn_body<2>(qs, kb, vT, attn, o, r0, h, buf); break;
        case 3: attn_body<3>(qs, kb, vT, attn, o, r0, h, buf); break;
        default: attn_body<4>(qs, kb, vT, attn, o, r0, h, buf); break;
    }
}

extern "C" void kernel_launch(void* const* d_in, const int* in_sizes, int n_in,
                              void* d_out, int out_size, void* d_ws, size_t ws_size,
                              hipStream_t stream) {
    const float* hidden = (const float*)d_in[0];
    const float* cosb   = (const float*)d_in[1];
    const float* sinb   = (const float*)d_in[2];
    const float* wq     = (const float*)d_in[3];
    const float* wk     = (const float*)d_in[4];
    const float* wv     = (const float*)d_in[5];
    const float* wo     = (const float*)d_in[6];
    char* ws = (char*)d_ws;
    bf16*  bf_hidden = (bf16*)(ws);                    // 8 MB; reused as O bf16 later
    bf16*  bf_wqkv   = (bf16*)(ws + 8388608);          // 12 MB
    bf16*  bf_wo     = (bf16*)(ws + 20971520);         // 8 MB
    float* qkv_raw   = (float*)(ws + 29360128);        // 24 MB
    bf16*  qsb       = (bf16*)(ws + 54525952);         // 8 MB  [H][S][HD]
    bf16*  kbb       = (bf16*)(ws + 62914560);         // 2 MB  [4][S][HD]
    bf16*  vTb       = (bf16*)(ws + 65011712);         // 2 MB  [4][HD][S]
    float* out  = (float*)d_out;
    float* attn = out + 4194304;

    cvt_all<<<dim3(14336), 256, 0, stream>>>(hidden, wq, wk, wv, wo, bf_hidden, bf_wqkv, bf_wo);

    // QKV projection: [2048 x 2048] @ [3072 x 2048]^T
    gemm128_bt<<<dim3(16, 24), 256, 0, stream>>>(bf_hidden, bf_wqkv, qkv_raw, NQKV, DM);

    rope_qk<<<dim3(10, S), 256, 0, stream>>>(qkv_raw, cosb, sinb, qsb, kbb);
    vtrans<<<dim3(32, 8), 256, 0, stream>>>(qkv_raw, vTb);

    // fused scores + entmax + P.V + attn write  (single dispatch, all classes)
    attn_av_all<<<dim3(128, H), 1024, 0, stream>>>(qsb, kbb, vTb, attn, bf_hidden);

    // out = O @ wo^T
    gemm128_bt<<<dim3(16, 16), 256, 0, stream>>>(bf_hidden, bf_wo, out, DM, DM);
}

// Round 8
// 648.426 us; speedup vs baseline: 1.0285x; 1.0285x over previous
//
#include <hip/hip_runtime.h>

typedef __bf16 bf16;
typedef __bf16 bf16x4 __attribute__((ext_vector_type(4)));
typedef __bf16 bf16x8 __attribute__((ext_vector_type(8)));
typedef float f32x4 __attribute__((ext_vector_type(4)));

#define S 2048
#define DM 2048
#define HD 128
#define H 16
#define NQKV 3072
#define NEWTON_ITERS 12

__device__ __forceinline__ void gl2lds16(const void* g, void* l) {
    __builtin_amdgcn_global_load_lds(
        (const __attribute__((address_space(1))) void*)g,
        (__attribute__((address_space(3))) void*)l, 16, 0, 0);
}

__device__ __forceinline__ void nt_store4(f32x4 v, float* p) {
    __builtin_nontemporal_store(v, (f32x4*)p);
}

// ---------------- fused fp32 -> bf16 convert for all 5 inputs (float4 granules) ----------------
__global__ void cvt_all(const float* __restrict__ hid, const float* __restrict__ wq,
                        const float* __restrict__ wk, const float* __restrict__ wv,
                        const float* __restrict__ wo, bf16* __restrict__ bh,
                        bf16* __restrict__ bqkv, bf16* __restrict__ bwo) {
    int i = blockIdx.x * blockDim.x + threadIdx.x;
    const float* src;
    bf16* dst;
    int off;
    if (i < 1048576) { src = hid; dst = bh; off = i; }
    else if (i < 2097152) { src = wq; dst = bqkv; off = i - 1048576; }
    else if (i < 2359296) { src = wk; dst = bqkv + 2048 * 2048; off = i - 2097152; }
    else if (i < 2621440) { src = wv; dst = bqkv + 2048 * 2048 + 512 * 2048; off = i - 2359296; }
    else { src = wo; dst = bwo; off = i - 2621440; }
    float4 f = ((const float4*)src)[off];
    bf16x4 o;
    o[0] = (bf16)f.x; o[1] = (bf16)f.y; o[2] = (bf16)f.z; o[3] = (bf16)f.w;
    ((bf16x4*)dst)[off] = o;
}

// ---------------- 128x128-tile GEMM: C[m][n] = sum_k A[m][k]*B[n][k] ----------------
__global__ __launch_bounds__(256) void gemm128_bt(const bf16* __restrict__ A,
                                                  const bf16* __restrict__ B,
                                                  float* __restrict__ C, int Ndim, int K) {
    __shared__ bf16 As[128 * 32];
    __shared__ bf16 Bs[128 * 32];
    int m0 = blockIdx.x * 128, n0 = blockIdx.y * 128;
    int t = threadIdx.x;
    int l = t & 63, w = t >> 6;
    int lane16 = l & 15, quad = l >> 4;

    int c0 = (w * 2) * 64 + l;
    int c1 = c0 + 64;
    const bf16* Abase = A + (size_t)m0 * K;
    const bf16* Bbase = B + (size_t)n0 * K;

    int wm = (w & 1) * 64, wn = (w >> 1) * 64;
    f32x4 acc[4][4];
#pragma unroll
    for (int i = 0; i < 4; i++)
#pragma unroll
        for (int j = 0; j < 4; j++) acc[i][j] = (f32x4){0.f, 0.f, 0.f, 0.f};

    for (int k0 = 0; k0 < K; k0 += 32) {
        gl2lds16(Abase + (size_t)(c0 >> 2) * K + k0 + (c0 & 3) * 8, &As[(w * 2) * 512]);
        gl2lds16(Abase + (size_t)(c1 >> 2) * K + k0 + (c1 & 3) * 8, &As[(w * 2 + 1) * 512]);
        gl2lds16(Bbase + (size_t)(c0 >> 2) * K + k0 + (c0 & 3) * 8, &Bs[(w * 2) * 512]);
        gl2lds16(Bbase + (size_t)(c1 >> 2) * K + k0 + (c1 & 3) * 8, &Bs[(w * 2 + 1) * 512]);
        __syncthreads();
        bf16x8 af[4], bfr[4];
#pragma unroll
        for (int i = 0; i < 4; i++)
            af[i] = *(const bf16x8*)&As[(wm + i * 16 + lane16) * 32 + quad * 8];
#pragma unroll
        for (int j = 0; j < 4; j++)
            bfr[j] = *(const bf16x8*)&Bs[(wn + j * 16 + lane16) * 32 + quad * 8];
#pragma unroll
        for (int i = 0; i < 4; i++)
#pragma unroll
            for (int j = 0; j < 4; j++)
                acc[i][j] = __builtin_amdgcn_mfma_f32_16x16x32_bf16(af[i], bfr[j], acc[i][j], 0, 0, 0);
        __syncthreads();
    }
#pragma unroll
    for (int i = 0; i < 4; i++)
#pragma unroll
        for (int j = 0; j < 4; j++) {
            float* cp = C + (size_t)(m0 + wm + i * 16 + quad * 4) * Ndim + n0 + wn + j * 16 + lane16;
#pragma unroll
            for (int r = 0; r < 4; r++) cp[(size_t)r * Ndim] = acc[i][j][r];
        }
}

// ---------------- RoPE for q/k (cols 0..2559), coalesced in col ----------------
__global__ void rope_qk(const float* __restrict__ qkv, const float* __restrict__ cosb,
                        const float* __restrict__ sinb, bf16* __restrict__ qs,
                        bf16* __restrict__ kb) {
    int col = blockIdx.x * 256 + threadIdx.x;  // 0..2559
    int s = blockIdx.y;
    const float* row = qkv + (size_t)s * NQKV;
    float v = row[col];
    if (col < DM) {
        int h = col >> 7, d = col & 127;
        float c = cosb[s * HD + d], sn = sinb[s * HD + d];
        float other = row[(h << 7) + ((d < 64) ? (d + 64) : (d - 64))];
        float rot = (d < 64) ? -other : other;
        float o = v * c + rot * sn;
        qs[((size_t)h * S + s) * HD + d] = (bf16)(o * 0.04419417382415922f);  // HD^-0.5 * (alpha-1)
    } else {
        int c2 = col - DM;
        int kv = c2 >> 7, d = c2 & 127;
        float c = cosb[s * HD + d], sn = sinb[s * HD + d];
        float other = row[DM + (kv << 7) + ((d < 64) ? (d + 64) : (d - 64))];
        float rot = (d < 64) ? -other : other;
        float o = v * c + rot * sn;
        kb[((size_t)kv * S + s) * HD + d] = (bf16)o;
    }
}

// ---------------- V transpose via LDS tile: qkv[s][2560+y] -> vT[y][s] bf16 ----------------
__global__ __launch_bounds__(256) void vtrans(const float* __restrict__ qkv, bf16* __restrict__ vT) {
    __shared__ bf16 tile[64][66];
    int s0 = blockIdx.x * 64, y0 = blockIdx.y * 64;
    int t = threadIdx.x;
    int ty = t & 63, tr = t >> 6;
#pragma unroll
    for (int i = 0; i < 16; i++) {
        int s = tr + i * 4;
        float v = qkv[(size_t)(s0 + s) * NQKV + 2560 + y0 + ty];  // coalesced read
        tile[s][ty] = (bf16)v;
    }
    __syncthreads();
#pragma unroll
    for (int i = 0; i < 16; i++) {
        int y = tr + i * 4;
        vT[(size_t)(y0 + y) * S + s0 + ty] = tile[ty][y];  // coalesced write
    }
}

// ------- fused: scores (MFMA) + causal mask + entmax Newton + P.V (MFMA) + attn write -------
template <int SEGS>
__device__ __forceinline__ void attn_body(const bf16* __restrict__ qs, const bf16* __restrict__ kb,
                                          const bf16* __restrict__ vT, float* __restrict__ attn,
                                          bf16* __restrict__ o, int r0, int h,
                                          float (&buf)[2][16][532]) {
    constexpr int NREG = SEGS * 8;
    int jlen = r0 + 16;
    int l = threadIdx.x & 63;
    int w = threadIdx.x >> 6;
    int lane16 = l & 15, quad = l >> 4;

    const bf16* qrow = qs + ((size_t)h * S + (r0 + lane16)) * HD + quad * 8;
    bf16x8 afrag[4];
#pragma unroll
    for (int kc = 0; kc < 4; kc++) afrag[kc] = *(const bf16x8*)(qrow + kc * 32);

    const bf16* kbase = kb + (size_t)(h >> 2) * S * HD;
    const bf16* vbase = vT + (size_t)(h >> 2) * HD * S;
    float xr[NREG];

    // ---- Phase A: scores into registers; ping-pong buffer, 1 barrier/segment ----
#pragma unroll
    for (int sgi = 0; sgi < SEGS; sgi++) {
        int j0 = sgi * 512;
        float (*sb)[532] = buf[sgi & 1];
#pragma unroll
        for (int tt = 0; tt < 2; tt++) {
            int t = w + tt * 16;
            int jt = j0 + t * 16;
            if (jt < jlen) {
                f32x4 acc = {0.f, 0.f, 0.f, 0.f};
                const bf16* kp = kbase + (size_t)(jt + lane16) * HD + quad * 8;
#pragma unroll
                for (int kc = 0; kc < 4; kc++) {
                    bf16x8 b = *(const bf16x8*)(kp + kc * 32);
                    acc = __builtin_amdgcn_mfma_f32_16x16x32_bf16(afrag[kc], b, acc, 0, 0, 0);
                }
                if (jt + 15 > r0) {  // diagonal tile: apply causal mask
                    int jj = jt + lane16;
#pragma unroll
                    for (int r = 0; r < 4; r++) {
                        int rowi = quad * 4 + r;
                        float v = acc[r];
                        if (jj > r0 + rowi) v = -1e30f;
                        sb[rowi][t * 16 + lane16] = v;
                    }
                } else {
#pragma unroll
                    for (int r = 0; r < 4; r++) sb[quad * 4 + r][t * 16 + lane16] = acc[r];
                }
            }
        }
        __syncthreads();
        if (sgi == SEGS - 1) {
#pragma unroll
            for (int part = 0; part < 2; part++) {
                float4 f = *(const float4*)&sb[w][part * 256 + l * 4];
                int jb = j0 + part * 256 + l * 4;
                xr[sgi * 8 + part * 4 + 0] = (jb + 0 < jlen) ? f.x : -1e30f;
                xr[sgi * 8 + part * 4 + 1] = (jb + 1 < jlen) ? f.y : -1e30f;
                xr[sgi * 8 + part * 4 + 2] = (jb + 2 < jlen) ? f.z : -1e30f;
                xr[sgi * 8 + part * 4 + 3] = (jb + 3 < jlen) ? f.w : -1e30f;
            }
        } else {
#pragma unroll
            for (int part = 0; part < 2; part++) {
                float4 f = *(const float4*)&sb[w][part * 256 + l * 4];
                xr[sgi * 8 + part * 4 + 0] = f.x;
                xr[sgi * 8 + part * 4 + 1] = f.y;
                xr[sgi * 8 + part * 4 + 2] = f.z;
                xr[sgi * 8 + part * 4 + 3] = f.w;
            }
        }
    }

    // ---- Phase B: entmax-1.5 tau via Newton-from-below (wave w owns row r0+w) ----
    float m = -1e30f;
#pragma unroll
    for (int c = 0; c < NREG; c++) m = fmaxf(m, xr[c]);
#pragma unroll
    for (int off = 1; off < 64; off <<= 1) m = fmaxf(m, __shfl_xor(m, off));

    float tau = m - 1.0f;
#pragma unroll 1
    for (int it = 0; it < NEWTON_ITERS; it++) {
        float f0 = 0.f, f1 = 0.f, f2 = 0.f, f3 = 0.f;
        float g0 = 0.f, g1 = 0.f, g2 = 0.f, g3 = 0.f;
#pragma unroll
        for (int c = 0; c < NREG; c += 4) {
            float t0 = fmaxf(xr[c + 0] - tau, 0.f); f0 = fmaf(t0, t0, f0); g0 += t0;
            float t1 = fmaxf(xr[c + 1] - tau, 0.f); f1 = fmaf(t1, t1, f1); g1 += t1;
            float t2 = fmaxf(xr[c + 2] - tau, 0.f); f2 = fmaf(t2, t2, f2); g2 += t2;
            float t3 = fmaxf(xr[c + 3] - tau, 0.f); f3 = fmaf(t3, t3, f3); g3 += t3;
        }
        float f = (f0 + f1) + (f2 + f3);
        float g = (g0 + g1) + (g2 + g3);
#pragma unroll
        for (int off = 1; off < 64; off <<= 1) {
            f += __shfl_xor(f, off);
            g += __shfl_xor(g, off);
        }
        tau += (f - 1.0f) / (2.0f * g + 1e-20f);
    }

    float s0 = 0.f, s1 = 0.f, s2 = 0.f, s3 = 0.f;
#pragma unroll
    for (int c = 0; c < NREG; c += 4) {
        float t0 = fmaxf(xr[c + 0] - tau, 0.f); s0 = fmaf(t0, t0, s0);
        float t1 = fmaxf(xr[c + 1] - tau, 0.f); s1 = fmaf(t1, t1, s1);
        float t2 = fmaxf(xr[c + 2] - tau, 0.f); s2 = fmaf(t2, t2, s2);
        float t3 = fmaxf(xr[c + 3] - tau, 0.f); s3 = fmaf(t3, t3, s3);
    }
    float ssum = (s0 + s1) + (s2 + s3);
#pragma unroll
    for (int off = 1; off < 64; off <<= 1) ssum += __shfl_xor(ssum, off);
    float inv = 1.0f / ssum;

    // ---- Phase C: P -> LDS bf16 (ping-pong), P.V MFMA; 1 barrier/segment ----
    int jt_o = (w & 7) * 16;
    int kh = (w >> 3) * 256;
    f32x4 acc_o = {0.f, 0.f, 0.f, 0.f};

    __syncthreads();
#pragma unroll
    for (int sgi = 0; sgi < SEGS; sgi++) {
        int j0 = sgi * 512;
        bf16 (*pbf)[552] = (bf16(*)[552])(&buf[sgi & 1][0][0]);
#pragma unroll
        for (int part = 0; part < 2; part++) {
            float t0 = fmaxf(xr[sgi * 8 + part * 4 + 0] - tau, 0.f);
            float t1 = fmaxf(xr[sgi * 8 + part * 4 + 1] - tau, 0.f);
            float t2 = fmaxf(xr[sgi * 8 + part * 4 + 2] - tau, 0.f);
            float t3 = fmaxf(xr[sgi * 8 + part * 4 + 3] - tau, 0.f);
            bf16x4 pbv;
            pbv[0] = (bf16)(t0 * t0 * inv); pbv[1] = (bf16)(t1 * t1 * inv);
            pbv[2] = (bf16)(t2 * t2 * inv); pbv[3] = (bf16)(t3 * t3 * inv);
            *(bf16x4*)&pbf[w][part * 256 + l * 4] = pbv;
        }
        __syncthreads();
#pragma unroll
        for (int ks = 0; ks < 8; ks++) {
            int kk = kh + ks * 32;
            bf16x8 a = *(const bf16x8*)&pbf[lane16][kk + quad * 8];
            bf16x8 b = *(const bf16x8*)(vbase + (size_t)(jt_o + lane16) * S + j0 + kk + quad * 8);
            acc_o = __builtin_amdgcn_mfma_f32_16x16x32_bf16(a, b, acc_o, 0, 0, 0);
        }
    }

    // ---- Phase D: combine K-halves, write O ----
    __syncthreads();
    if (w >= 8) {
#pragma unroll
        for (int r = 0; r < 4; r++) buf[0][w - 8][l * 4 + r] = acc_o[r];
    }
    __syncthreads();
    if (w < 8) {
        bf16* op = o + (size_t)(r0 + quad * 4) * DM + h * HD + jt_o + lane16;
#pragma unroll
        for (int r = 0; r < 4; r++) {
            float v = acc_o[r] + buf[0][w][l * 4 + r];
            op[(size_t)r * DM] = (bf16)v;
        }
    }

    // ---- Phase E: attn global write (nontemporal, after the last barrier) ----
    float* arow = attn + ((size_t)h * S + (r0 + w)) * S;
#pragma unroll
    for (int sgi = 0; sgi < SEGS; sgi++) {
        int j0 = sgi * 512;
#pragma unroll
        for (int part = 0; part < 2; part++) {
            float t0 = fmaxf(xr[sgi * 8 + part * 4 + 0] - tau, 0.f);
            float t1 = fmaxf(xr[sgi * 8 + part * 4 + 1] - tau, 0.f);
            float t2 = fmaxf(xr[sgi * 8 + part * 4 + 2] - tau, 0.f);
            float t3 = fmaxf(xr[sgi * 8 + part * 4 + 3] - tau, 0.f);
            f32x4 pv;
            pv[0] = t0 * t0 * inv; pv[1] = t1 * t1 * inv;
            pv[2] = t2 * t2 * inv; pv[3] = t3 * t3 * inv;
            nt_store4(pv, &arow[j0 + part * 256 + l * 4]);
        }
    }
    f32x4 z4 = {0.f, 0.f, 0.f, 0.f};
    for (int j = SEGS * 512 + l * 4; j < S; j += 256) nt_store4(z4, &arow[j]);
}

// Persistent workgroups: 512 blocks (2/CU), each runs one item of every causal class
// {1,2,3,4} segments -> exactly 10 segments per block, perfectly uniform load.
__global__ __launch_bounds__(1024) void attn_av_all(const bf16* __restrict__ qs,
                                                    const bf16* __restrict__ kb,
                                                    const bf16* __restrict__ vT,
                                                    float* __restrict__ attn,
                                                    bf16* __restrict__ o) {
    __shared__ float buf[2][16][532];  // 68 KB
    int b = blockIdx.x;      // 0..511
    int h = b & 15;
    int qh = b >> 4;         // 0..31
    attn_body<4>(qs, kb, vT, attn, o, (96 + qh) * 16, h, buf);
    __syncthreads();
    attn_body<3>(qs, kb, vT, attn, o, (64 + qh) * 16, h, buf);
    __syncthreads();
    attn_body<2>(qs, kb, vT, attn, o, (32 + qh) * 16, h, buf);
    __syncthreads();
    attn_body<1>(qs, kb, vT, attn, o, qh * 16, h, buf);
}

extern "C" void kernel_launch(void* const* d_in, const int* in_sizes, int n_in,
                              void* d_out, int out_size, void* d_ws, size_t ws_size,
                              hipStream_t stream) {
    const float* hidden = (const float*)d_in[0];
    const float* cosb   = (const float*)d_in[1];
    const float* sinb   = (const float*)d_in[2];
    const float* wq     = (const float*)d_in[3];
    const float* wk     = (const float*)d_in[4];
    const float* wv     = (const float*)d_in[5];
    const float* wo     = (const float*)d_in[6];
    char* ws = (char*)d_ws;
    bf16*  bf_hidden = (bf16*)(ws);                    // 8 MB; reused as O bf16 later
    bf16*  bf_wqkv   = (bf16*)(ws + 8388608);          // 12 MB
    bf16*  bf_wo     = (bf16*)(ws + 20971520);         // 8 MB
    float* qkv_raw   = (float*)(ws + 29360128);        // 24 MB
    bf16*  qsb       = (bf16*)(ws + 54525952);         // 8 MB  [H][S][HD]
    bf16*  kbb       = (bf16*)(ws + 62914560);         // 2 MB  [4][S][HD]
    bf16*  vTb       = (bf16*)(ws + 65011712);         // 2 MB  [4][HD][S]
    float* out  = (float*)d_out;
    float* attn = out + 4194304;

    cvt_all<<<dim3(14336), 256, 0, stream>>>(hidden, wq, wk, wv, wo, bf_hidden, bf_wqkv, bf_wo);

    // QKV projection: [2048 x 2048] @ [3072 x 2048]^T
    gemm128_bt<<<dim3(16, 24), 256, 0, stream>>>(bf_hidden, bf_wqkv, qkv_raw, NQKV, DM);

    rope_qk<<<dim3(10, S), 256, 0, stream>>>(qkv_raw, cosb, sinb, qsb, kbb);
    vtrans<<<dim3(32, 8), 256, 0, stream>>>(qkv_raw, vTb);

    // fused scores + entmax + P.V + attn write  (512 persistent blocks)
    attn_av_all<<<dim3(512), 1024, 0, stream>>>(qsb, kbb, vTb, attn, bf_hidden);

    // out = O @ wo^T
    gemm128_bt<<<dim3(16, 16), 256, 0, stream>>>(bf_hidden, bf_wo, out, DM, DM);
}